// Round 9
// baseline (332.819 us; speedup 1.0000x reference)
//
#include <hip/hip_runtime.h>
#include <hip/hip_cooperative_groups.h>
#include <stdint.h>

namespace cg = cooperative_groups;

// Problem constants (B=8, T=2048, D=256, K=8192)
#define M_TOK 16384
#define DIM   256
#define KCB   8192
#define NGRP  8                    // N-groups
#define GRP   1024                 // codes per group
#define NCHK  32                   // 16B k-chunks per row (256*2B/16B)
#define NT    16                   // 64-code tiles per group
#define NBLK  512                  // cooperative grid: 2 blocks/CU on 256 CUs
#define SHIFT 512.0f               // positivity shift for score packing
#define INV_N (1.0f / 4194304.0f)  // 1/(B*T*D)

typedef __attribute__((ext_vector_type(4))) float f32x4;
typedef __attribute__((ext_vector_type(8))) __bf16 bf16x8;

static __device__ __forceinline__ unsigned short f2bf(float f) {
    uint32_t x = __float_as_uint(f);
    uint32_t r = (x + 0x7fffu + ((x >> 16) & 1u)) >> 16;   // RNE
    return (unsigned short)r;
}

static __device__ __forceinline__ bf16x8 cvt8(float4 a, float4 b) {
    union { unsigned short u[8]; bf16x8 v; } r;
    r.u[0] = f2bf(a.x); r.u[1] = f2bf(a.y); r.u[2] = f2bf(a.z); r.u[3] = f2bf(a.w);
    r.u[4] = f2bf(b.x); r.u[5] = f2bf(b.y); r.u[6] = f2bf(b.z); r.u[7] = f2bf(b.w);
    return r.v;
}

// Async global->LDS DMA, 16 B/lane; LDS dest = wave-uniform base + lane*16.
static __device__ __forceinline__ void lds_cp16(const void* g, void* l) {
    __builtin_amdgcn_global_load_lds(
        (const __attribute__((address_space(1))) void*)g,
        (__attribute__((address_space(3))) void*)l, 16, 0, 0);
}

// ======================================================================
// Fused cooperative kernel. Static LDS EXACTLY 65536 B (R8's 69632 B is
// the suspected cooperative-launch rejection: occupancy validator budgets
// sharedMemPerBlock=64KiB). One buffer aliased by phase:
//   GEMM phase:  Bs[2][NCHK][64][8] (65536 B)
//   other phases: scratch floats (prep reduce / finalize / final write)
// chalf is read from global (4KB, L1-hot) instead of LDS.
// ======================================================================
typedef unsigned short BsT[NCHK][64][8];

__global__ __launch_bounds__(256, 2) void k_mega(
    const float* __restrict__ xs,            // [M_TOK][DIM] fp32
    const float* __restrict__ cb,            // [KCB][DIM]   fp32
    unsigned short* __restrict__ cbt,        // [NCHK][KCB][8] bf16 of -c
    float* __restrict__ chalf,               // [KCB]
    uint32_t* __restrict__ pkey,             // [M_TOK][NGRP]
    float* __restrict__ partial,             // [NBLK]
    float* __restrict__ out)                 // [2]
{
    __shared__ __align__(16) unsigned char shm[65536];
    BsT*   Bs      = (BsT*)shm;              // [2] x 32 KB (GEMM phase only)
    float* scratch = (float*)shm;            // other phases only

    cg::grid_group grid = cg::this_grid();
    const int b   = blockIdx.x;
    const int tid = threadIdx.x;
    const int w   = tid >> 6;
    const int l   = tid & 63;

    // ===== Phase 1: codebook prep (blocks 0..127, 64 codes each)
    if (b < 128) {
        const int c0 = b * 64;
        const float* row = cb + (size_t)(c0 + l) * DIM;
        float s = 0.0f;
        #pragma unroll
        for (int j = 0; j < 8; j++) {
            int cr = w * 8 + j;
            float4 f0 = *(const float4*)(row + cr * 8);
            float4 f1 = *(const float4*)(row + cr * 8 + 4);
            s += f0.x * f0.x + f0.y * f0.y + f0.z * f0.z + f0.w * f0.w +
                 f1.x * f1.x + f1.y * f1.y + f1.z * f1.z + f1.w * f1.w;
            union { unsigned short u[8]; uint4 q; } r;
            r.u[0] = f2bf(-f0.x); r.u[1] = f2bf(-f0.y);
            r.u[2] = f2bf(-f0.z); r.u[3] = f2bf(-f0.w);
            r.u[4] = f2bf(-f1.x); r.u[5] = f2bf(-f1.y);
            r.u[6] = f2bf(-f1.z); r.u[7] = f2bf(-f1.w);
            *(uint4*)(cbt + ((size_t)cr * KCB + c0 + l) * 8) = r.q;
        }
        scratch[w * 64 + l] = s;
        __syncthreads();
        if (w == 0) {
            float t = scratch[l] + scratch[64 + l] +
                      scratch[128 + l] + scratch[192 + l];
            chalf[c0 + l] = 0.5f * t + SHIFT;
        }
    }
    grid.sync();

    // ===== Phase 2: double-buffered GEMM + argmin (R7 body, chalf global)
    {
        const int lrow = l & 15;
        const int quad = l >> 4;
        const int m0 = (b >> 3) * 256;
        const int g  = b & 7;
        const float* cp = chalf + g * GRP;

        const unsigned short* bsrc =
            cbt + ((size_t)(w * 8) * KCB + g * GRP + l) * 8;

        #pragma unroll
        for (int j = 0; j < 8; j++)
            lds_cp16(bsrc + (size_t)j * KCB * 8, &Bs[0][w * 8 + j][0][0]);

        bf16x8 afr[4][8];
        {
            const float* ap = xs + (size_t)(m0 + w * 64 + lrow) * DIM + quad * 8;
            #pragma unroll
            for (int rt = 0; rt < 4; rt++)
                #pragma unroll
                for (int kt = 0; kt < 8; kt++) {
                    const float* p = ap + rt * 16 * DIM + kt * 32;
                    float4 f0 = *(const float4*)p;
                    float4 f1 = *(const float4*)(p + 4);
                    afr[rt][kt] = cvt8(f0, f1);
                }
        }

        uint32_t best[4][4];
        #pragma unroll
        for (int rt = 0; rt < 4; rt++)
            #pragma unroll
            for (int rg = 0; rg < 4; rg++) best[rt][rg] = 0xFFFFFFFFu;

        #pragma unroll 1
        for (int t = 0; t < NT; t++) {
            const int cur = t & 1;
            __syncthreads();   // drains DMA(t) issued one compute phase ago
            if (t < NT - 1) {  // prefetch t+1 AFTER the barrier
                #pragma unroll
                for (int j = 0; j < 8; j++)
                    lds_cp16(bsrc + ((size_t)j * KCB + (t + 1) * 64) * 8,
                             &Bs[1 - cur][w * 8 + j][0][0]);
            }

            f32x4 acc[4][4];
            #pragma unroll
            for (int ct = 0; ct < 4; ct++) {
                float cs = cp[t * 64 + ct * 16 + lrow];
                #pragma unroll
                for (int rt = 0; rt < 4; rt++) {
                    f32x4 c4 = {cs, cs, cs, cs};
                    acc[rt][ct] = c4;
                }
            }
            #pragma unroll
            for (int bk = 0; bk < 8; bk++) {
                bf16x8 bfr[4];
                #pragma unroll
                for (int ct = 0; ct < 4; ct++)
                    bfr[ct] = *(const bf16x8*)&Bs[cur][bk * 4 + quad]
                                                 [ct * 16 + lrow][0];
                #pragma unroll
                for (int rt = 0; rt < 4; rt++)
                    #pragma unroll
                    for (int ct = 0; ct < 4; ct++)
                        acc[rt][ct] = __builtin_amdgcn_mfma_f32_16x16x32_bf16(
                            afr[rt][bk], bfr[ct], acc[rt][ct], 0, 0, 0);
            }
            #pragma unroll
            for (int ct = 0; ct < 4; ct++) {
                uint32_t idl = (uint32_t)(t * 64 + ct * 16 + lrow);
                #pragma unroll
                for (int rt = 0; rt < 4; rt++)
                    #pragma unroll
                    for (int rg = 0; rg < 4; rg++) {
                        uint32_t key =
                            (__float_as_uint(acc[rt][ct][rg]) & 0xFFFFFC00u) | idl;
                        if (key < best[rt][rg]) best[rt][rg] = key;
                    }
            }
        }

        #pragma unroll
        for (int off = 1; off < 16; off <<= 1)
            #pragma unroll
            for (int rt = 0; rt < 4; rt++)
                #pragma unroll
                for (int rg = 0; rg < 4; rg++) {
                    uint32_t o = __shfl_xor(best[rt][rg], off);
                    if (o < best[rt][rg]) best[rt][rg] = o;
                }
        if (lrow == 0) {
            #pragma unroll
            for (int rt = 0; rt < 4; rt++)
                #pragma unroll
                for (int rg = 0; rg < 4; rg++)
                    pkey[(size_t)(m0 + w * 64 + rt * 16 + quad * 4 + rg) * NGRP + g]
                        = best[rt][rg];
        }
    }
    grid.sync();

    // ===== Phase 3: finalize 32 rows/block (8 lanes per row)
    {
        const int r   = tid >> 3;
        const int gq  = tid & 7;
        const int row = b * 32 + r;
        uint32_t k = pkey[(size_t)row * NGRP + gq];
        int gi = gq;
        #pragma unroll
        for (int off = 1; off < 8; off <<= 1) {
            uint32_t ok = __shfl_xor(k, off);
            int      og = __shfl_xor(gi, off);
            if (ok < k) { k = ok; gi = og; }
        }
        int code = gi * GRP + (int)(k & 1023u);
        const float4* x4 = (const float4*)xs + (size_t)row * 64;
        const float4* c4 = (const float4*)cb + (size_t)code * 64;
        float s = 0.0f;
        #pragma unroll
        for (int i = 0; i < 8; i++) {
            int j = gq + 8 * i;
            float4 x = x4[j], c = c4[j];
            float dx = x.x - c.x, dy = x.y - c.y, dz = x.z - c.z, dw = x.w - c.w;
            s += dx * dx + dy * dy + dz * dz + dw * dw;
        }
        #pragma unroll
        for (int off = 1; off < 64; off <<= 1) s += __shfl_xor(s, off);
        __syncthreads();             // Bs readers long done; reuse as scratch
        if (l == 0) scratch[w] = s;
        __syncthreads();
        if (tid == 0)
            partial[b] = scratch[0] + scratch[1] + scratch[2] + scratch[3];
    }
    grid.sync();

    // ===== Phase 4: block 0 reduces 512 partials
    if (b == 0) {
        float s = partial[tid] + partial[tid + 256];
        #pragma unroll
        for (int off = 32; off; off >>= 1) s += __shfl_xor(s, off);
        if (l == 0) scratch[w] = s;
        __syncthreads();
        if (tid == 0) {
            float tot = scratch[0] + scratch[1] + scratch[2] + scratch[3];
            float commit = tot * INV_N;
            out[0] = 0.25f * commit;   // loss
            out[1] = commit;           // commit_loss
        }
    }
}

// ======================================================================
// Fallback path: verbatim R7 kernels (known-good, 143.9 us) used only if
// hipLaunchCooperativeKernel is rejected.
// ======================================================================
__global__ void k_prep(const float* __restrict__ cb,
                       unsigned short* __restrict__ cbt,
                       float* __restrict__ chalf) {
    __shared__ float part[4][64];
    const int w  = threadIdx.x >> 6;
    const int l  = threadIdx.x & 63;
    const int c0 = blockIdx.x * 64;
    const float* row = cb + (size_t)(c0 + l) * DIM;
    float s = 0.0f;
    #pragma unroll
    for (int j = 0; j < 8; j++) {
        int cr = w * 8 + j;
        float4 f0 = *(const float4*)(row + cr * 8);
        float4 f1 = *(const float4*)(row + cr * 8 + 4);
        s += f0.x * f0.x + f0.y * f0.y + f0.z * f0.z + f0.w * f0.w +
             f1.x * f1.x + f1.y * f1.y + f1.z * f1.z + f1.w * f1.w;
        union { unsigned short u[8]; uint4 q; } r;
        r.u[0] = f2bf(-f0.x); r.u[1] = f2bf(-f0.y);
        r.u[2] = f2bf(-f0.z); r.u[3] = f2bf(-f0.w);
        r.u[4] = f2bf(-f1.x); r.u[5] = f2bf(-f1.y);
        r.u[6] = f2bf(-f1.z); r.u[7] = f2bf(-f1.w);
        *(uint4*)(cbt + ((size_t)cr * KCB + c0 + l) * 8) = r.q;
    }
    part[w][l] = s;
    __syncthreads();
    if (w == 0) {
        float t = part[0][l] + part[1][l] + part[2][l] + part[3][l];
        chalf[c0 + l] = 0.5f * t + SHIFT;
    }
}

__global__ __launch_bounds__(256, 2) void k_gemm_argmin(
    const float* __restrict__ xs,
    const unsigned short* __restrict__ cbt,
    const float* __restrict__ chalf,
    uint32_t* __restrict__ pkey)
{
    __shared__ __align__(16) unsigned short Bs[2][NCHK][64][8];
    __shared__ float schalf[GRP];

    const int tid  = threadIdx.x;
    const int w    = tid >> 6;
    const int l    = tid & 63;
    const int lrow = l & 15;
    const int quad = l >> 4;
    const int m0 = blockIdx.x * 256;
    const int g  = blockIdx.y;

    *(float4*)&schalf[tid * 4] = ((const float4*)(chalf + g * GRP))[tid];

    const unsigned short* bsrc = cbt + ((size_t)(w * 8) * KCB + g * GRP + l) * 8;

    #pragma unroll
    for (int j = 0; j < 8; j++)
        lds_cp16(bsrc + (size_t)j * KCB * 8, &Bs[0][w * 8 + j][0][0]);

    bf16x8 afr[4][8];
    {
        const float* ap = xs + (size_t)(m0 + w * 64 + lrow) * DIM + quad * 8;
        #pragma unroll
        for (int rt = 0; rt < 4; rt++)
            #pragma unroll
            for (int kt = 0; kt < 8; kt++) {
                const float* p = ap + rt * 16 * DIM + kt * 32;
                float4 f0 = *(const float4*)p;
                float4 f1 = *(const float4*)(p + 4);
                afr[rt][kt] = cvt8(f0, f1);
            }
    }

    uint32_t best[4][4];
    #pragma unroll
    for (int rt = 0; rt < 4; rt++)
        #pragma unroll
        for (int rg = 0; rg < 4; rg++) best[rt][rg] = 0xFFFFFFFFu;

    #pragma unroll 1
    for (int t = 0; t < NT; t++) {
        const int cur = t & 1;
        __syncthreads();
        if (t < NT - 1) {
            #pragma unroll
            for (int j = 0; j < 8; j++)
                lds_cp16(bsrc + ((size_t)j * KCB + (t + 1) * 64) * 8,
                         &Bs[1 - cur][w * 8 + j][0][0]);
        }

        f32x4 acc[4][4];
        #pragma unroll
        for (int ct = 0; ct < 4; ct++) {
            float cs = schalf[t * 64 + ct * 16 + lrow];
            #pragma unroll
            for (int rt = 0; rt < 4; rt++) {
                f32x4 c4 = {cs, cs, cs, cs};
                acc[rt][ct] = c4;
            }
        }
        #pragma unroll
        for (int bk = 0; bk < 8; bk++) {
            bf16x8 bfr[4];
            #pragma unroll
            for (int ct = 0; ct < 4; ct++)
                bfr[ct] = *(const bf16x8*)&Bs[cur][bk * 4 + quad][ct * 16 + lrow][0];
            #pragma unroll
            for (int rt = 0; rt < 4; rt++)
                #pragma unroll
                for (int ct = 0; ct < 4; ct++)
                    acc[rt][ct] = __builtin_amdgcn_mfma_f32_16x16x32_bf16(
                        afr[rt][bk], bfr[ct], acc[rt][ct], 0, 0, 0);
        }
        #pragma unroll
        for (int ct = 0; ct < 4; ct++) {
            uint32_t idl = (uint32_t)(t * 64 + ct * 16 + lrow);
            #pragma unroll
            for (int rt = 0; rt < 4; rt++)
                #pragma unroll
                for (int rg = 0; rg < 4; rg++) {
                    uint32_t key =
                        (__float_as_uint(acc[rt][ct][rg]) & 0xFFFFFC00u) | idl;
                    if (key < best[rt][rg]) best[rt][rg] = key;
                }
        }
    }

    #pragma unroll
    for (int off = 1; off < 16; off <<= 1)
        #pragma unroll
        for (int rt = 0; rt < 4; rt++)
            #pragma unroll
            for (int rg = 0; rg < 4; rg++) {
                uint32_t o = __shfl_xor(best[rt][rg], off);
                if (o < best[rt][rg]) best[rt][rg] = o;
            }
    if (lrow == 0) {
        #pragma unroll
        for (int rt = 0; rt < 4; rt++)
            #pragma unroll
            for (int rg = 0; rg < 4; rg++)
                pkey[(size_t)(m0 + w * 64 + rt * 16 + quad * 4 + rg) * NGRP + g]
                    = best[rt][rg];
    }
}

__global__ void k_finalize(const uint32_t* __restrict__ pkey,
                           const float4* __restrict__ xs4,
                           const float4* __restrict__ cb4,
                           float* __restrict__ partial) {
    __shared__ float sblk[4];
    int w   = threadIdx.x >> 6;
    int row = blockIdx.x * 4 + w;
    int l   = threadIdx.x & 63;
    uint32_t k = 0xFFFFFFFFu;
    int g = 0;
    if (l < 8) { k = pkey[(size_t)row * NGRP + l]; g = l; }
    #pragma unroll
    for (int off = 1; off < 8; off <<= 1) {
        uint32_t ok = __shfl_xor(k, off);
        int      og = __shfl_xor(g, off);
        if (ok < k) { k = ok; g = og; }
    }
    k = __shfl(k, 0);
    g = __shfl(g, 0);
    int code = g * GRP + (int)(k & 1023u);
    float4 x = xs4[(size_t)row * 64 + l];
    float4 c = cb4[(size_t)code * 64 + l];
    float dx = x.x - c.x, dy = x.y - c.y, dz = x.z - c.z, dw = x.w - c.w;
    float s = dx * dx + dy * dy + dz * dz + dw * dw;
    #pragma unroll
    for (int off = 32; off; off >>= 1) s += __shfl_xor(s, off);
    if (l == 0) sblk[w] = s;
    __syncthreads();
    if (threadIdx.x == 0)
        partial[blockIdx.x] = sblk[0] + sblk[1] + sblk[2] + sblk[3];
}

__global__ void k_write(const float* __restrict__ partial, int n,
                        float* __restrict__ out) {
    __shared__ float swv[16];
    int tid = threadIdx.x;
    float s = 0.0f;
    for (int i = tid; i < n; i += 1024) s += partial[i];
    #pragma unroll
    for (int off = 32; off; off >>= 1) s += __shfl_xor(s, off);
    if ((tid & 63) == 0) swv[tid >> 6] = s;
    __syncthreads();
    if (tid == 0) {
        float t = 0.0f;
        #pragma unroll
        for (int i = 0; i < 16; i++) t += swv[i];
        float commit = t * INV_N;
        out[0] = 0.25f * commit;   // loss
        out[1] = commit;           // commit_loss
    }
}

extern "C" void kernel_launch(void* const* d_in, const int* in_sizes, int n_in,
                              void* d_out, int out_size, void* d_ws, size_t ws_size,
                              hipStream_t stream) {
    const float* xs = (const float*)d_in[0];
    // d_in[1] = ilens (int64, all == T) -> slice is a no-op, unused
    const float* cb = (const float*)d_in[2];

    char* ws = (char*)d_ws;
    unsigned short* cbt     = (unsigned short*)(ws + 256);          // 4 MiB
    float*          chalf   = (float*)(ws + 256 + 4194304);         // 32 KiB
    uint32_t*       pkey    = (uint32_t*)(ws + 256 + 4227072);      // 512 KiB
    float*          partial = (float*)(ws + 256 + 4751360);         // 16 KiB
    float*          out     = (float*)d_out;

    void* args[] = { (void*)&xs, (void*)&cb, (void*)&cbt, (void*)&chalf,
                     (void*)&pkey, (void*)&partial, (void*)&out };
    hipError_t err = hipLaunchCooperativeKernel(
        (const void*)k_mega, dim3(NBLK), dim3(256), args, 0, stream);

    if (err != hipSuccess) {
        // Fallback: R7 4-kernel sequence (known-good).
        k_prep<<<128, 256, 0, stream>>>(cb, cbt, chalf);
        dim3 g(M_TOK / 256, NGRP);
        k_gemm_argmin<<<g, 256, 0, stream>>>(xs, cbt, chalf, pkey);
        k_finalize<<<4096, 256, 0, stream>>>(pkey, (const float4*)xs,
                                             (const float4*)cb, partial);
        k_write<<<1, 1024, 0, stream>>>(partial, 4096, out);
    }
}

// Round 10
// 184.770 us; speedup vs baseline: 1.8013x; 1.8013x over previous
//
#include <hip/hip_runtime.h>
#include <stdint.h>

// Problem constants (B=8, T=2048, D=256, K=8192)
#define M_TOK 16384
#define DIM   256
#define KCB   8192
#define NGRP  8                    // N-groups
#define GRP   1024                 // codes per group
#define NCHK  32                   // 16B k-chunks per row (256*2B/16B)
#define NT    16                   // 64-code tiles per group
#define SHIFT 512.0f               // positivity shift for score packing
#define INV_N (1.0f / 4194304.0f)  // 1/(B*T*D)

typedef __attribute__((ext_vector_type(4))) float f32x4;
typedef __attribute__((ext_vector_type(8))) __bf16 bf16x8;

static __device__ __forceinline__ unsigned short f2bf(float f) {
    uint32_t x = __float_as_uint(f);
    uint32_t r = (x + 0x7fffu + ((x >> 16) & 1u)) >> 16;   // RNE
    return (unsigned short)r;
}

static __device__ __forceinline__ bf16x8 cvt8(float4 a, float4 b) {
    union { unsigned short u[8]; bf16x8 v; } r;
    r.u[0] = f2bf(a.x); r.u[1] = f2bf(a.y); r.u[2] = f2bf(a.z); r.u[3] = f2bf(a.w);
    r.u[4] = f2bf(b.x); r.u[5] = f2bf(b.y); r.u[6] = f2bf(b.z); r.u[7] = f2bf(b.w);
    return r.v;
}

// Async global->LDS DMA, 16 B/lane; LDS dest = wave-uniform base + lane*16.
static __device__ __forceinline__ void lds_cp16(const void* g, void* l) {
    __builtin_amdgcn_global_load_lds(
        (const __attribute__((address_space(1))) void*)g,
        (__attribute__((address_space(3))) void*)l, 16, 0, 0);
}

// ---------------------------------------------------------------- kernel 1
// Codebook prep (R7 body) + block 0 zeroes the completion counters
// (ws is re-poisoned to 0xAA before every launch).
__global__ void k_prep(const float* __restrict__ cb,
                       unsigned short* __restrict__ cbt,
                       float* __restrict__ chalf,
                       int* __restrict__ cnt) {
    __shared__ float part[4][64];
    const int w  = threadIdx.x >> 6;
    const int l  = threadIdx.x & 63;
    const int c0 = blockIdx.x * 64;
    if (blockIdx.x == 0 && threadIdx.x < 65) cnt[threadIdx.x] = 0;
    const float* row = cb + (size_t)(c0 + l) * DIM;
    float s = 0.0f;
    #pragma unroll
    for (int j = 0; j < 8; j++) {
        int cr = w * 8 + j;
        float4 f0 = *(const float4*)(row + cr * 8);
        float4 f1 = *(const float4*)(row + cr * 8 + 4);
        s += f0.x * f0.x + f0.y * f0.y + f0.z * f0.z + f0.w * f0.w +
             f1.x * f1.x + f1.y * f1.y + f1.z * f1.z + f1.w * f1.w;
        union { unsigned short u[8]; uint4 q; } r;
        r.u[0] = f2bf(-f0.x); r.u[1] = f2bf(-f0.y);
        r.u[2] = f2bf(-f0.z); r.u[3] = f2bf(-f0.w);
        r.u[4] = f2bf(-f1.x); r.u[5] = f2bf(-f1.y);
        r.u[6] = f2bf(-f1.z); r.u[7] = f2bf(-f1.w);
        *(uint4*)(cbt + ((size_t)cr * KCB + c0 + l) * 8) = r.q;
    }
    part[w][l] = s;
    __syncthreads();
    if (w == 0) {
        float t = part[0][l] + part[1][l] + part[2][l] + part[3][l];
        chalf[c0 + l] = 0.5f * t + SHIFT;
    }
}

// ---------------------------------------------------------------- kernel 2
// R7 double-buffered GEMM+argmin (body unchanged), plus a fused tail:
// pkey layout is GROUP-MAJOR [NGRP][M_TOK] (each block's 256 stores are one
// contiguous 1KB run -> no cross-XCD line sharing). After storing, each
// block: release fence + atomicAdd(cnt[m]); the 8th arriver finalizes its
// 256 rows (exact fp32 distance) -> partial[m]; the 64th finalizer writes
// the two output scalars. No grid-wide sync (R9: grid.sync L2-thrash).
__global__ __launch_bounds__(256, 2) void k_gemm_fin(
    const float* __restrict__ xs,              // [M_TOK][DIM] fp32
    const float* __restrict__ cb,              // [KCB][DIM]   fp32
    const unsigned short* __restrict__ cbt,    // [NCHK][KCB][8] bf16 of -c
    const float* __restrict__ chalf,           // [KCB]
    uint32_t* __restrict__ pkey,               // [NGRP][M_TOK]
    float* __restrict__ partial,               // [64]
    int* __restrict__ cnt,                     // [65]
    float* __restrict__ out)                   // [2]
{
    __shared__ __align__(16) unsigned short Bs[2][NCHK][64][8];   // 64 KB
    __shared__ float schalf[GRP];                                  // 4 KB
    __shared__ float sred[4];
    __shared__ int   sArr, sArr2;

    const int tid  = threadIdx.x;
    const int w    = tid >> 6;
    const int l    = tid & 63;
    const int lrow = l & 15;
    const int quad = l >> 4;
    const int bx = blockIdx.x;            // m-block 0..63
    const int m0 = bx * 256;
    const int g  = blockIdx.y;

    *(float4*)&schalf[tid * 4] = ((const float4*)(chalf + g * GRP))[tid];

    const unsigned short* bsrc = cbt + ((size_t)(w * 8) * KCB + g * GRP + l) * 8;

    #pragma unroll
    for (int j = 0; j < 8; j++)
        lds_cp16(bsrc + (size_t)j * KCB * 8, &Bs[0][w * 8 + j][0][0]);

    bf16x8 afr[4][8];
    {
        const float* ap = xs + (size_t)(m0 + w * 64 + lrow) * DIM + quad * 8;
        #pragma unroll
        for (int rt = 0; rt < 4; rt++)
            #pragma unroll
            for (int kt = 0; kt < 8; kt++) {
                const float* p = ap + rt * 16 * DIM + kt * 32;
                float4 f0 = *(const float4*)p;
                float4 f1 = *(const float4*)(p + 4);
                afr[rt][kt] = cvt8(f0, f1);
            }
    }

    uint32_t best[4][4];
    #pragma unroll
    for (int rt = 0; rt < 4; rt++)
        #pragma unroll
        for (int rg = 0; rg < 4; rg++) best[rt][rg] = 0xFFFFFFFFu;

    #pragma unroll 1
    for (int t = 0; t < NT; t++) {
        const int cur = t & 1;
        __syncthreads();   // drains DMA(t) issued one compute phase ago
        if (t < NT - 1) {  // prefetch t+1 AFTER the barrier
            #pragma unroll
            for (int j = 0; j < 8; j++)
                lds_cp16(bsrc + ((size_t)j * KCB + (t + 1) * 64) * 8,
                         &Bs[1 - cur][w * 8 + j][0][0]);
        }

        f32x4 acc[4][4];
        #pragma unroll
        for (int ct = 0; ct < 4; ct++) {
            float cs = schalf[t * 64 + ct * 16 + lrow];
            #pragma unroll
            for (int rt = 0; rt < 4; rt++) {
                f32x4 c4 = {cs, cs, cs, cs};
                acc[rt][ct] = c4;
            }
        }
        #pragma unroll
        for (int bk = 0; bk < 8; bk++) {
            bf16x8 bfr[4];
            #pragma unroll
            for (int ct = 0; ct < 4; ct++)
                bfr[ct] = *(const bf16x8*)&Bs[cur][bk * 4 + quad][ct * 16 + lrow][0];
            #pragma unroll
            for (int rt = 0; rt < 4; rt++)
                #pragma unroll
                for (int ct = 0; ct < 4; ct++)
                    acc[rt][ct] = __builtin_amdgcn_mfma_f32_16x16x32_bf16(
                        afr[rt][bk], bfr[ct], acc[rt][ct], 0, 0, 0);
        }
        #pragma unroll
        for (int ct = 0; ct < 4; ct++) {
            uint32_t idl = (uint32_t)(t * 64 + ct * 16 + lrow);
            #pragma unroll
            for (int rt = 0; rt < 4; rt++)
                #pragma unroll
                for (int rg = 0; rg < 4; rg++) {
                    uint32_t key =
                        (__float_as_uint(acc[rt][ct][rg]) & 0xFFFFFC00u) | idl;
                    if (key < best[rt][rg]) best[rt][rg] = key;
                }
        }
    }

    #pragma unroll
    for (int off = 1; off < 16; off <<= 1)
        #pragma unroll
        for (int rt = 0; rt < 4; rt++)
            #pragma unroll
            for (int rg = 0; rg < 4; rg++) {
                uint32_t o = __shfl_xor(best[rt][rg], off);
                if (o < best[rt][rg]) best[rt][rg] = o;
            }
    if (lrow == 0) {
        #pragma unroll
        for (int rt = 0; rt < 4; rt++)
            #pragma unroll
            for (int rg = 0; rg < 4; rg++)
                pkey[(size_t)g * M_TOK + m0 + w * 64 + rt * 16 + quad * 4 + rg]
                    = best[rt][rg];
    }

    // ================= fused tail: last arriver per m-block finalizes
    __syncthreads();               // all waves' pkey stores issued+drained
    __threadfence();               // release (L2 writeback)
    if (tid == 0) sArr = atomicAdd(&cnt[bx], 1);
    __syncthreads();
    if (sArr != 7) return;         // not the 8th arriver

    __threadfence();               // acquire (invalidate stale lines)
    float fsum = 0.0f;
    const int r8 = tid >> 3, gq = tid & 7;
    const float4* xs4 = (const float4*)xs;
    const float4* cb4 = (const float4*)cb;
    #pragma unroll 1
    for (int pass = 0; pass < 8; pass++) {
        int row = m0 + pass * 32 + r8;
        uint32_t k = pkey[(size_t)gq * M_TOK + row];
        int gi = gq;
        #pragma unroll
        for (int off = 1; off < 8; off <<= 1) {
            uint32_t ok = __shfl_xor(k, off);
            int      og = __shfl_xor(gi, off);
            if (ok < k) { k = ok; gi = og; }
        }
        int code = gi * GRP + (int)(k & 1023u);
        const float4* x4 = xs4 + (size_t)row * 64;
        const float4* c4 = cb4 + (size_t)code * 64;
        #pragma unroll
        for (int i = 0; i < 8; i++) {
            int j = gq + 8 * i;
            float4 x = x4[j], c = c4[j];
            float dx = x.x - c.x, dy = x.y - c.y, dz = x.z - c.z, dw = x.w - c.w;
            fsum += dx * dx + dy * dy + dz * dz + dw * dw;
        }
    }
    #pragma unroll
    for (int off = 1; off < 64; off <<= 1) fsum += __shfl_xor(fsum, off);
    if (l == 0) sred[w] = fsum;
    __syncthreads();
    if (tid == 0) {
        partial[bx] = sred[0] + sred[1] + sred[2] + sred[3];
        __threadfence();           // release partial[bx]
        sArr2 = atomicAdd(&cnt[64], 1);
    }
    __syncthreads();
    if (sArr2 != 63) return;       // not the last finalizer

    __threadfence();               // acquire partials
    if (w == 0) {
        float s = partial[l];      // 64 lanes, 64 partials
        #pragma unroll
        for (int off = 1; off < 64; off <<= 1) s += __shfl_xor(s, off);
        if (l == 0) {
            float commit = s * INV_N;
            out[0] = 0.25f * commit;   // loss
            out[1] = commit;           // commit_loss
        }
    }
}

extern "C" void kernel_launch(void* const* d_in, const int* in_sizes, int n_in,
                              void* d_out, int out_size, void* d_ws, size_t ws_size,
                              hipStream_t stream) {
    const float* xs = (const float*)d_in[0];
    // d_in[1] = ilens (int64, all == T) -> slice is a no-op, unused
    const float* cb = (const float*)d_in[2];

    char* ws = (char*)d_ws;
    unsigned short* cbt     = (unsigned short*)(ws + 256);          // 4 MiB
    float*          chalf   = (float*)(ws + 256 + 4194304);         // 32 KiB
    uint32_t*       pkey    = (uint32_t*)(ws + 256 + 4227072);      // 512 KiB
    float*          partial = (float*)(ws + 256 + 4751360);         // 256 B
    int*            cnt     = (int*)  (ws + 256 + 4751616);         // 260 B
    float*          out     = (float*)d_out;

    k_prep<<<128, 256, 0, stream>>>(cb, cbt, chalf, cnt);
    dim3 g(M_TOK / 256, NGRP);
    k_gemm_fin<<<g, 256, 0, stream>>>(xs, cb, cbt, chalf, pkey, partial, cnt, out);
}

// Round 11
// 120.345 us; speedup vs baseline: 2.7655x; 1.5353x over previous
//
#include <hip/hip_runtime.h>
#include <stdint.h>

// Problem constants (B=8, T=2048, D=256, K=8192)
#define M_TOK 16384
#define DIM   256
#define KCB   8192
#define NGRP  8                    // N-groups (blocks in y)
#define GRP   1024                 // codes per group
#define NCHK  16                   // 16B fp8 k-chunks per row (256*1B/16B)
#define NT    16                   // 64-code tiles per group
#define SHIFT 512.0f               // positivity shift for score packing
#define INV_N (1.0f / 4194304.0f)  // 1/(B*T*D)
#define SC1   0x7F7F7F7F           // E8M0 scale bytes = 2^0 (op_sel-proof)

typedef __attribute__((ext_vector_type(4))) float f32x4;
typedef __attribute__((ext_vector_type(8))) int   i32x8;

// Async global->LDS DMA, 16 B/lane; LDS dest = wave-uniform base + lane*16.
static __device__ __forceinline__ void lds_cp16(const void* g, void* l) {
    __builtin_amdgcn_global_load_lds(
        (const __attribute__((address_space(1))) void*)g,
        (__attribute__((address_space(3))) void*)l, 16, 0, 0);
}

// pack 4 floats -> 4 fp8 e4m3 bytes (one dword)
static __device__ __forceinline__ int pk4(float4 f) {
    int o = __builtin_amdgcn_cvt_pk_fp8_f32(f.x, f.y, 0, false);
    o     = __builtin_amdgcn_cvt_pk_fp8_f32(f.z, f.w, o, true);
    return o;
}

// ---------------------------------------------------------------- kernel 1
// Codebook prep: cbt[chunk][code][16B] = fp8 of -c, k-chunk-major (GEMM LDS
// staging reads 1KB-contiguous); chalf = 0.5||c||^2 + SHIFT (exact fp32).
// Block = 64 codes; wave w handles k-chunks [4w, 4w+4); lane = code.
__global__ void k_prep(const float* __restrict__ cb,
                       unsigned char* __restrict__ cbt,
                       float* __restrict__ chalf) {
    __shared__ float part[4][64];
    const int w  = threadIdx.x >> 6;
    const int l  = threadIdx.x & 63;
    const int c0 = blockIdx.x * 64;
    const float* row = cb + (size_t)(c0 + l) * DIM;
    float s = 0.0f;
    #pragma unroll
    for (int j = 0; j < 4; j++) {
        int ch = w * 4 + j;
        const float* p = row + ch * 16;
        float4 a = *(const float4*)(p);
        float4 b = *(const float4*)(p + 4);
        float4 c = *(const float4*)(p + 8);
        float4 d = *(const float4*)(p + 12);
        s += a.x*a.x + a.y*a.y + a.z*a.z + a.w*a.w
           + b.x*b.x + b.y*b.y + b.z*b.z + b.w*b.w
           + c.x*c.x + c.y*c.y + c.z*c.z + c.w*c.w
           + d.x*d.x + d.y*d.y + d.z*d.z + d.w*d.w;
        float4 na = {-a.x, -a.y, -a.z, -a.w};
        float4 nb = {-b.x, -b.y, -b.z, -b.w};
        float4 nc = {-c.x, -c.y, -c.z, -c.w};
        float4 nd = {-d.x, -d.y, -d.z, -d.w};
        uint4 r;
        r.x = (unsigned)pk4(na); r.y = (unsigned)pk4(nb);
        r.z = (unsigned)pk4(nc); r.w = (unsigned)pk4(nd);
        *(uint4*)(cbt + ((size_t)ch * KCB + c0 + l) * 16) = r;
    }
    part[w][l] = s;
    __syncthreads();
    if (w == 0) {
        float t = part[0][l] + part[1][l] + part[2][l] + part[3][l];
        chalf[c0 + l] = 0.5f * t + SHIFT;
    }
}

// ---------------------------------------------------------------- kernel 2
// fp8-MX double-buffered GEMM+argmin (R7 skeleton). grid (64, 8), 4 waves;
// block = 256 rows x 64-code tiles. Wave = 64 rows x 64 codes: rt=4, ct=4,
// ksteps=2 (K=128 per MFMA). A panel: fp32 load -> fp8 cvt in-reg (64 VGPR).
// B tiles: fp8 in LDS (2 x 16 KB dbuf), staged via global_load_lds; one
// barrier per tile drains the DMA issued one full compute phase earlier.
// acc init = 0.5||c||^2+SHIFT (fp32, exact), B = -c  =>  acc = positive
// score. Scales fixed 2^0 -> pure fp8 GEMM at the MX (2x bf16) rate.
__global__ __launch_bounds__(256, 2) void k_gemm_argmin(
    const float* __restrict__ xs,              // [M_TOK][DIM] fp32
    const unsigned char* __restrict__ cbt,     // [NCHK][KCB][16] fp8 of -c
    const float* __restrict__ chalf,           // [KCB] = 0.5||c||^2+SHIFT
    uint32_t* __restrict__ pkey)               // [M_TOK][NGRP]
{
    __shared__ __align__(16) unsigned char Bs[2][NCHK][64][16];   // 32 KB
    __shared__ float schalf[GRP];                                  // 4 KB

    const int tid  = threadIdx.x;
    const int w    = tid >> 6;
    const int l    = tid & 63;
    const int lrow = l & 15;
    const int quad = l >> 4;
    const int m0 = blockIdx.x * 256;
    const int g  = blockIdx.y;

    *(float4*)&schalf[tid * 4] = ((const float4*)(chalf + g * GRP))[tid];

    // staging: wave w supplies chunks [4w,4w+4); lane = code in tile
    const unsigned char* bsrc = cbt + ((size_t)(w * 4) * KCB + g * GRP + l) * 16;

    #pragma unroll
    for (int j = 0; j < 4; j++)
        lds_cp16(bsrc + (size_t)j * KCB * 16, &Bs[0][w * 4 + j][0][0]);

    // ---- A panel: 64 rows x 256 k, fp32 -> fp8 frags (4 rt x 2 ks x 8 dw)
    i32x8 afr[4][2];
    {
        const float* ap = xs + (size_t)(m0 + w * 64 + lrow) * DIM + quad * 32;
        #pragma unroll
        for (int rt = 0; rt < 4; rt++)
            #pragma unroll
            for (int ks = 0; ks < 2; ks++) {
                const float* p = ap + rt * 16 * DIM + ks * 128;
                union { int d[8]; i32x8 v; } aa;
                #pragma unroll
                for (int d = 0; d < 8; d++)
                    aa.d[d] = pk4(*(const float4*)(p + d * 4));
                afr[rt][ks] = aa.v;
            }
    }

    uint32_t best[4][4];
    #pragma unroll
    for (int rt = 0; rt < 4; rt++)
        #pragma unroll
        for (int rg = 0; rg < 4; rg++) best[rt][rg] = 0xFFFFFFFFu;

    #pragma unroll 1
    for (int t = 0; t < NT; t++) {
        const int cur = t & 1;
        __syncthreads();   // drains DMA(t) issued one compute phase ago
        if (t < NT - 1) {  // prefetch t+1 AFTER the barrier
            #pragma unroll
            for (int j = 0; j < 4; j++)
                lds_cp16(bsrc + ((size_t)j * KCB + (t + 1) * 64) * 16,
                         &Bs[1 - cur][w * 4 + j][0][0]);
        }

        f32x4 acc[4][4];
        #pragma unroll
        for (int ct = 0; ct < 4; ct++) {
            float cs = schalf[t * 64 + ct * 16 + lrow];
            #pragma unroll
            for (int rt = 0; rt < 4; rt++) {
                f32x4 c4 = {cs, cs, cs, cs};
                acc[rt][ct] = c4;
            }
        }
        #pragma unroll
        for (int ks = 0; ks < 2; ks++) {
            const int ch = ks * 8 + quad * 2;   // lane's k-window = 2 chunks
            i32x8 bfr[4];
            #pragma unroll
            for (int ct = 0; ct < 4; ct++) {
                union { uint4 q[2]; i32x8 v; } bb;
                bb.q[0] = *(const uint4*)&Bs[cur][ch][ct * 16 + lrow][0];
                bb.q[1] = *(const uint4*)&Bs[cur][ch + 1][ct * 16 + lrow][0];
                bfr[ct] = bb.v;
            }
            #pragma unroll
            for (int rt = 0; rt < 4; rt++)
                #pragma unroll
                for (int ct = 0; ct < 4; ct++)
                    acc[rt][ct] = __builtin_amdgcn_mfma_scale_f32_16x16x128_f8f6f4(
                        afr[rt][ks], bfr[ct], acc[rt][ct],
                        0, 0,              // cbsz, blgp: fmt 0 = fp8 e4m3
                        0, SC1,            // op_sel_a, scale_a = 2^0
                        0, SC1);           // op_sel_b, scale_b = 2^0
        }
        // fold scores into packed keys: (score_bits & ~1023) | group-local id
        #pragma unroll
        for (int ct = 0; ct < 4; ct++) {
            uint32_t idl = (uint32_t)(t * 64 + ct * 16 + lrow);
            #pragma unroll
            for (int rt = 0; rt < 4; rt++)
                #pragma unroll
                for (int rg = 0; rg < 4; rg++) {
                    uint32_t key =
                        (__float_as_uint(acc[rt][ct][rg]) & 0xFFFFFC00u) | idl;
                    if (key < best[rt][rg]) best[rt][rg] = key;
                }
        }
    }

    // min across the 16 lanes of each quad group (same rows, different codes)
    #pragma unroll
    for (int off = 1; off < 16; off <<= 1)
        #pragma unroll
        for (int rt = 0; rt < 4; rt++)
            #pragma unroll
            for (int rg = 0; rg < 4; rg++) {
                uint32_t o = __shfl_xor(best[rt][rg], off);
                if (o < best[rt][rg]) best[rt][rg] = o;
            }
    if (lrow == 0) {
        #pragma unroll
        for (int rt = 0; rt < 4; rt++)
            #pragma unroll
            for (int rg = 0; rg < 4; rg++)
                pkey[(size_t)(m0 + w * 64 + rt * 16 + quad * 4 + rg) * NGRP + g]
                    = best[rt][rg];
    }
}

// ---------------------------------------------------------------- kernel 3
// Per row: min over 8 group keys -> final code; exact fp32 ||x-c||^2;
// per-block LDS reduce -> partial[blockIdx]. No global atomics/fences.
__global__ void k_finalize(const uint32_t* __restrict__ pkey,
                           const float4* __restrict__ xs4,
                           const float4* __restrict__ cb4,
                           float* __restrict__ partial) {
    __shared__ float sblk[4];
    int w   = threadIdx.x >> 6;
    int row = blockIdx.x * 4 + w;
    int l   = threadIdx.x & 63;
    uint32_t k = 0xFFFFFFFFu;
    int g = 0;
    if (l < 8) { k = pkey[(size_t)row * NGRP + l]; g = l; }
    #pragma unroll
    for (int off = 1; off < 8; off <<= 1) {
        uint32_t ok = __shfl_xor(k, off);
        int      og = __shfl_xor(g, off);
        if (ok < k) { k = ok; g = og; }
    }
    k = __shfl(k, 0);
    g = __shfl(g, 0);
    int code = g * GRP + (int)(k & 1023u);
    float4 x = xs4[(size_t)row * 64 + l];
    float4 c = cb4[(size_t)code * 64 + l];
    float dx = x.x - c.x, dy = x.y - c.y, dz = x.z - c.z, dw = x.w - c.w;
    float s = dx * dx + dy * dy + dz * dz + dw * dw;
    #pragma unroll
    for (int off = 32; off; off >>= 1) s += __shfl_xor(s, off);
    if (l == 0) sblk[w] = s;
    __syncthreads();
    if (threadIdx.x == 0)
        partial[blockIdx.x] = sblk[0] + sblk[1] + sblk[2] + sblk[3];
}

// ---------------------------------------------------------------- kernel 4
__global__ void k_write(const float* __restrict__ partial,
                        float* __restrict__ out) {
    __shared__ float swv[16];
    int tid = threadIdx.x;                    // 1024 threads = 16 waves
    float s = partial[tid] + partial[tid + 1024] +
              partial[tid + 2048] + partial[tid + 3072];
    #pragma unroll
    for (int off = 32; off; off >>= 1) s += __shfl_xor(s, off);
    if ((tid & 63) == 0) swv[tid >> 6] = s;
    __syncthreads();
    if (tid == 0) {
        float t = 0.0f;
        #pragma unroll
        for (int i = 0; i < 16; i++) t += swv[i];
        float commit = t * INV_N;
        out[0] = 0.25f * commit;   // loss
        out[1] = commit;           // commit_loss
    }
}

extern "C" void kernel_launch(void* const* d_in, const int* in_sizes, int n_in,
                              void* d_out, int out_size, void* d_ws, size_t ws_size,
                              hipStream_t stream) {
    const float* xs = (const float*)d_in[0];
    // d_in[1] = ilens (int64, all == T) -> slice is a no-op, unused
    const float* cb = (const float*)d_in[2];

    char* ws = (char*)d_ws;
    unsigned char* cbt     = (unsigned char*)(ws + 256);            // 2 MiB
    float*         chalf   = (float*)(ws + 256 + 2097152);          // 32 KiB
    uint32_t*      pkey    = (uint32_t*)(ws + 256 + 2129920);       // 512 KiB
    float*         partial = (float*)(ws + 256 + 2654208);          // 16 KiB

    k_prep<<<128, 256, 0, stream>>>(cb, cbt, chalf);
    dim3 g(M_TOK / 256, NGRP);
    k_gemm_argmin<<<g, 256, 0, stream>>>(xs, cbt, chalf, pkey);
    k_finalize<<<4096, 256, 0, stream>>>(pkey, (const float4*)xs,
                                         (const float4*)cb, partial);
    k_write<<<1, 1024, 0, stream>>>(partial, (float*)d_out);
}

// Round 12
// 119.427 us; speedup vs baseline: 2.7868x; 1.0077x over previous
//
#include <hip/hip_runtime.h>
#include <stdint.h>

// Problem constants (B=8, T=2048, D=256, K=8192)
#define M_TOK 16384
#define DIM   256
#define KCB   8192
#define NGRP  8                    // N-groups (blocks in y)
#define GRP   1024                 // codes per group
#define NCHK  16                   // 16B fp8 k-chunks per row (256*1B/16B)
#define NT    16                   // 64-code tiles per group
#define SHIFT 512.0f               // positivity shift for score packing
#define INV_N (1.0f / 4194304.0f)  // 1/(B*T*D)
#define SC1   0x7F7F7F7F           // E8M0 scale bytes = 2^0 (op_sel-proof)

typedef __attribute__((ext_vector_type(4))) float f32x4;
typedef __attribute__((ext_vector_type(8))) int   i32x8;

// Async global->LDS DMA, 16 B/lane; LDS dest = wave-uniform base + lane*16.
static __device__ __forceinline__ void lds_cp16(const void* g, void* l) {
    __builtin_amdgcn_global_load_lds(
        (const __attribute__((address_space(1))) void*)g,
        (__attribute__((address_space(3))) void*)l, 16, 0, 0);
}

// pack 4 floats -> 4 fp8 e4m3 bytes (one dword)
static __device__ __forceinline__ int pk4(float4 f) {
    int o = __builtin_amdgcn_cvt_pk_fp8_f32(f.x, f.y, 0, false);
    o     = __builtin_amdgcn_cvt_pk_fp8_f32(f.z, f.w, o, true);
    return o;
}

// ---------------------------------------------------------------- kernel 1
// Codebook prep: cbt[chunk][code][16B] = fp8 of -c, k-chunk-major (GEMM LDS
// staging reads 1KB-contiguous); chalf = 0.5||c||^2 + SHIFT (exact fp32).
// Block = 64 codes; wave w handles k-chunks [4w, 4w+4); lane = code.
__global__ void k_prep(const float* __restrict__ cb,
                       unsigned char* __restrict__ cbt,
                       float* __restrict__ chalf) {
    __shared__ float part[4][64];
    const int w  = threadIdx.x >> 6;
    const int l  = threadIdx.x & 63;
    const int c0 = blockIdx.x * 64;
    const float* row = cb + (size_t)(c0 + l) * DIM;
    float s = 0.0f;
    #pragma unroll
    for (int j = 0; j < 4; j++) {
        int ch = w * 4 + j;
        const float* p = row + ch * 16;
        float4 a = *(const float4*)(p);
        float4 b = *(const float4*)(p + 4);
        float4 c = *(const float4*)(p + 8);
        float4 d = *(const float4*)(p + 12);
        s += a.x*a.x + a.y*a.y + a.z*a.z + a.w*a.w
           + b.x*b.x + b.y*b.y + b.z*b.z + b.w*b.w
           + c.x*c.x + c.y*c.y + c.z*c.z + c.w*c.w
           + d.x*d.x + d.y*d.y + d.z*d.z + d.w*d.w;
        float4 na = {-a.x, -a.y, -a.z, -a.w};
        float4 nb = {-b.x, -b.y, -b.z, -b.w};
        float4 nc = {-c.x, -c.y, -c.z, -c.w};
        float4 nd = {-d.x, -d.y, -d.z, -d.w};
        uint4 r;
        r.x = (unsigned)pk4(na); r.y = (unsigned)pk4(nb);
        r.z = (unsigned)pk4(nc); r.w = (unsigned)pk4(nd);
        *(uint4*)(cbt + ((size_t)ch * KCB + c0 + l) * 16) = r;
    }
    part[w][l] = s;
    __syncthreads();
    if (w == 0) {
        float t = part[0][l] + part[1][l] + part[2][l] + part[3][l];
        chalf[c0 + l] = 0.5f * t + SHIFT;
    }
}

// ---------------------------------------------------------------- kernel 2
// fp8-MX double-buffered GEMM+argmin. R12 change: 128-row blocks, grid
// (128, 8) = 1024 blocks = 4 blocks/CU (R11 ran 2/CU; 47% of cycles were
// latency/barrier stalls with only 2 waves/SIMD). Wave = 32 rows (rt=2) x
// 64 codes (ct=4), ksteps=2 (K=128/MFMA). LDS 36 KB, VGPR target <=128
// via __launch_bounds__(256,4) -> 4 waves/SIMD latency hiding.
__global__ __launch_bounds__(256, 4) void k_gemm_argmin(
    const float* __restrict__ xs,              // [M_TOK][DIM] fp32
    const unsigned char* __restrict__ cbt,     // [NCHK][KCB][16] fp8 of -c
    const float* __restrict__ chalf,           // [KCB] = 0.5||c||^2+SHIFT
    uint32_t* __restrict__ pkey)               // [M_TOK][NGRP]
{
    __shared__ __align__(16) unsigned char Bs[2][NCHK][64][16];   // 32 KB
    __shared__ float schalf[GRP];                                  // 4 KB

    const int tid  = threadIdx.x;
    const int w    = tid >> 6;
    const int l    = tid & 63;
    const int lrow = l & 15;
    const int quad = l >> 4;
    const int m0 = blockIdx.x * 128;
    const int g  = blockIdx.y;

    *(float4*)&schalf[tid * 4] = ((const float4*)(chalf + g * GRP))[tid];

    // staging: wave w supplies chunks [4w,4w+4); lane = code in tile
    const unsigned char* bsrc = cbt + ((size_t)(w * 4) * KCB + g * GRP + l) * 16;

    #pragma unroll
    for (int j = 0; j < 4; j++)
        lds_cp16(bsrc + (size_t)j * KCB * 16, &Bs[0][w * 4 + j][0][0]);

    // ---- A panel: 32 rows x 256 k, fp32 -> fp8 frags (2 rt x 2 ks x 8 dw)
    i32x8 afr[2][2];
    {
        const float* ap = xs + (size_t)(m0 + w * 32 + lrow) * DIM + quad * 32;
        #pragma unroll
        for (int rt = 0; rt < 2; rt++)
            #pragma unroll
            for (int ks = 0; ks < 2; ks++) {
                const float* p = ap + rt * 16 * DIM + ks * 128;
                union { int d[8]; i32x8 v; } aa;
                #pragma unroll
                for (int d = 0; d < 8; d++)
                    aa.d[d] = pk4(*(const float4*)(p + d * 4));
                afr[rt][ks] = aa.v;
            }
    }

    uint32_t best[2][4];
    #pragma unroll
    for (int rt = 0; rt < 2; rt++)
        #pragma unroll
        for (int rg = 0; rg < 4; rg++) best[rt][rg] = 0xFFFFFFFFu;

    #pragma unroll 1
    for (int t = 0; t < NT; t++) {
        const int cur = t & 1;
        __syncthreads();   // drains DMA(t) issued one compute phase ago
        if (t < NT - 1) {  // prefetch t+1 AFTER the barrier
            #pragma unroll
            for (int j = 0; j < 4; j++)
                lds_cp16(bsrc + ((size_t)j * KCB + (t + 1) * 64) * 16,
                         &Bs[1 - cur][w * 4 + j][0][0]);
        }

        f32x4 acc[2][4];
        #pragma unroll
        for (int ct = 0; ct < 4; ct++) {
            float cs = schalf[t * 64 + ct * 16 + lrow];
            #pragma unroll
            for (int rt = 0; rt < 2; rt++) {
                f32x4 c4 = {cs, cs, cs, cs};
                acc[rt][ct] = c4;
            }
        }
        #pragma unroll
        for (int ks = 0; ks < 2; ks++) {
            const int ch = ks * 8 + quad * 2;   // lane's k-window = 2 chunks
            i32x8 bfr[4];
            #pragma unroll
            for (int ct = 0; ct < 4; ct++) {
                union { uint4 q[2]; i32x8 v; } bb;
                bb.q[0] = *(const uint4*)&Bs[cur][ch][ct * 16 + lrow][0];
                bb.q[1] = *(const uint4*)&Bs[cur][ch + 1][ct * 16 + lrow][0];
                bfr[ct] = bb.v;
            }
            #pragma unroll
            for (int rt = 0; rt < 2; rt++)
                #pragma unroll
                for (int ct = 0; ct < 4; ct++)
                    acc[rt][ct] = __builtin_amdgcn_mfma_scale_f32_16x16x128_f8f6f4(
                        afr[rt][ks], bfr[ct], acc[rt][ct],
                        0, 0,              // cbsz, blgp: fmt 0 = fp8 e4m3
                        0, SC1,            // op_sel_a, scale_a = 2^0
                        0, SC1);           // op_sel_b, scale_b = 2^0
        }
        // fold scores into packed keys: (score_bits & ~1023) | group-local id
        #pragma unroll
        for (int ct = 0; ct < 4; ct++) {
            uint32_t idl = (uint32_t)(t * 64 + ct * 16 + lrow);
            #pragma unroll
            for (int rt = 0; rt < 2; rt++)
                #pragma unroll
                for (int rg = 0; rg < 4; rg++) {
                    uint32_t key =
                        (__float_as_uint(acc[rt][ct][rg]) & 0xFFFFFC00u) | idl;
                    if (key < best[rt][rg]) best[rt][rg] = key;
                }
        }
    }

    // min across the 16 lanes of each quad group (same rows, different codes)
    #pragma unroll
    for (int off = 1; off < 16; off <<= 1)
        #pragma unroll
        for (int rt = 0; rt < 2; rt++)
            #pragma unroll
            for (int rg = 0; rg < 4; rg++) {
                uint32_t o = __shfl_xor(best[rt][rg], off);
                if (o < best[rt][rg]) best[rt][rg] = o;
            }
    if (lrow == 0) {
        #pragma unroll
        for (int rt = 0; rt < 2; rt++)
            #pragma unroll
            for (int rg = 0; rg < 4; rg++)
                pkey[(size_t)(m0 + w * 32 + rt * 16 + quad * 4 + rg) * NGRP + g]
                    = best[rt][rg];
    }
}

// ---------------------------------------------------------------- kernel 3
// Per row: min over 8 group keys -> final code; exact fp32 ||x-c||^2;
// per-block LDS reduce -> partial[blockIdx]. No global atomics/fences.
__global__ void k_finalize(const uint32_t* __restrict__ pkey,
                           const float4* __restrict__ xs4,
                           const float4* __restrict__ cb4,
                           float* __restrict__ partial) {
    __shared__ float sblk[4];
    int w   = threadIdx.x >> 6;
    int row = blockIdx.x * 4 + w;
    int l   = threadIdx.x & 63;
    uint32_t k = 0xFFFFFFFFu;
    int g = 0;
    if (l < 8) { k = pkey[(size_t)row * NGRP + l]; g = l; }
    #pragma unroll
    for (int off = 1; off < 8; off <<= 1) {
        uint32_t ok = __shfl_xor(k, off);
        int      og = __shfl_xor(g, off);
        if (ok < k) { k = ok; g = og; }
    }
    k = __shfl(k, 0);
    g = __shfl(g, 0);
    int code = g * GRP + (int)(k & 1023u);
    float4 x = xs4[(size_t)row * 64 + l];
    float4 c = cb4[(size_t)code * 64 + l];
    float dx = x.x - c.x, dy = x.y - c.y, dz = x.z - c.z, dw = x.w - c.w;
    float s = dx * dx + dy * dy + dz * dz + dw * dw;
    #pragma unroll
    for (int off = 32; off; off >>= 1) s += __shfl_xor(s, off);
    if (l == 0) sblk[w] = s;
    __syncthreads();
    if (threadIdx.x == 0)
        partial[blockIdx.x] = sblk[0] + sblk[1] + sblk[2] + sblk[3];
}

// ---------------------------------------------------------------- kernel 4
__global__ void k_write(const float* __restrict__ partial,
                        float* __restrict__ out) {
    __shared__ float swv[16];
    int tid = threadIdx.x;                    // 1024 threads = 16 waves
    float s = partial[tid] + partial[tid + 1024] +
              partial[tid + 2048] + partial[tid + 3072];
    #pragma unroll
    for (int off = 32; off; off >>= 1) s += __shfl_xor(s, off);
    if ((tid & 63) == 0) swv[tid >> 6] = s;
    __syncthreads();
    if (tid == 0) {
        float t = 0.0f;
        #pragma unroll
        for (int i = 0; i < 16; i++) t += swv[i];
        float commit = t * INV_N;
        out[0] = 0.25f * commit;   // loss
        out[1] = commit;           // commit_loss
    }
}

extern "C" void kernel_launch(void* const* d_in, const int* in_sizes, int n_in,
                              void* d_out, int out_size, void* d_ws, size_t ws_size,
                              hipStream_t stream) {
    const float* xs = (const float*)d_in[0];
    // d_in[1] = ilens (int64, all == T) -> slice is a no-op, unused
    const float* cb = (const float*)d_in[2];

    char* ws = (char*)d_ws;
    unsigned char* cbt     = (unsigned char*)(ws + 256);            // 2 MiB
    float*         chalf   = (float*)(ws + 256 + 2097152);          // 32 KiB
    uint32_t*      pkey    = (uint32_t*)(ws + 256 + 2129920);       // 512 KiB
    float*         partial = (float*)(ws + 256 + 2654208);          // 16 KiB

    k_prep<<<128, 256, 0, stream>>>(cb, cbt, chalf);
    dim3 g(M_TOK / 128, NGRP);
    k_gemm_argmin<<<g, 256, 0, stream>>>(xs, cbt, chalf, pkey);
    k_finalize<<<4096, 256, 0, stream>>>(pkey, (const float4*)xs,
                                         (const float4*)cb, partial);
    k_write<<<1, 1024, 0, stream>>>(partial, (float*)d_out);
}